// Round 4
// baseline (3069.999 us; speedup 1.0000x reference)
//
#include <hip/hip_runtime.h>
#include <hip/hip_bf16.h>

#define N_IN      256
#define N_OUTC    128
#define RPS       64       // rows per superbin
#define RPS_SHIFT 6
#define NSB_MAX   1024
#define TILE      4096     // edges per build block
#define EPT       16       // edges per thread in build
#define SPILL_CAP 8192

typedef __attribute__((ext_vector_type(8))) short bf16x8;
typedef __attribute__((ext_vector_type(4))) float f32x4;
typedef unsigned short ushort_t;
typedef unsigned int uint_t;

__device__ inline unsigned short f2bf(float f) {
    unsigned u = __float_as_uint(f);
    unsigned r = u + 0x7fffu + ((u >> 16) & 1u);
    return (unsigned short)(r >> 16);
}
__device__ inline float bf_lo(uint_t g) { return __uint_as_float(g << 16); }
__device__ inline float bf_hi(uint_t g) { return __uint_as_float(g & 0xFFFF0000u); }

// ---------------- W fp32 [128,256] -> bf16 ----------------
__global__ void cvtW_kernel(const float* __restrict__ W, ushort_t* __restrict__ wb, int n) {
    int i = blockIdx.x * blockDim.x + threadIdx.x;
    if (i < n) wb[i] = f2bf(W[i]);
}

// ---------------- fused: buildA (blocks [0,nbBuild)) + gemm (rest) ----------------
// build: LDS-ranked superbin binning (one global atomic per (block,bin), NOT per edge).
// gemm: all 16 x-loads/lane hoisted into registers (VGPR ~110, 2 waves/EU) so
// the HBM read of x is fully pipelined instead of 2-deep at VGPR=32.
__global__ __launch_bounds__(256, 2) void fused_build_gemm_kernel(
        // build args
        const int* __restrict__ rows, const int* __restrict__ cols,
        const float* __restrict__ vals, int E,
        int* __restrict__ sbCount, int2* __restrict__ sbList, int sbCap, int nsb,
        int* __restrict__ spillCnt, int4* __restrict__ spill, int nbBuild,
        // gemm args
        const float* __restrict__ x, const ushort_t* __restrict__ wb,
        const float* __restrict__ b, ushort_t* __restrict__ h16) {
    __shared__ int cur[NSB_MAX];
    __shared__ int gbase[NSB_MAX];
    const int tid = threadIdx.x;

    if (blockIdx.x < (uint_t)nbBuild) {
        // ---- buildA ----
        const int base = blockIdx.x * TILE;
        for (int i = tid; i < nsb; i += 256) cur[i] = 0;
        __syncthreads();

        int ex[EPT], evb[EPT], esb[EPT], erk[EPT];
        #pragma unroll
        for (int k = 0; k < EPT; k++) {
            int e = base + tid + k * 256;
            if (e < E) {
                int r = rows[e], c = cols[e];
                evb[k] = __float_as_int(vals[e]);
                esb[k] = r >> RPS_SHIFT;
                ex[k]  = c | ((r & (RPS - 1)) << 17);
                erk[k] = atomicAdd(&cur[esb[k]], 1);
            } else esb[k] = -1;
        }
        __syncthreads();
        for (int i = tid; i < nsb; i += 256)
            gbase[i] = cur[i] ? atomicAdd(&sbCount[i], cur[i]) : 0;
        __syncthreads();

        #pragma unroll
        for (int k = 0; k < EPT; k++) {
            if (esb[k] < 0) continue;
            int pos = gbase[esb[k]] + erk[k];
            if (pos < sbCap) {
                sbList[(size_t)esb[k] * sbCap + pos] = make_int2(ex[k], evb[k]);
            } else {
                int sp = atomicAdd(spillCnt, 1);
                if (sp < SPILL_CAP)
                    spill[sp] = make_int4((esb[k] << RPS_SHIFT) + (int)(((uint_t)ex[k]) >> 17),
                                          ex[k] & 0x1FFFF, evb[k], 0);
            }
        }
        return;
    }

    // ---- gemm: h = x @ W^T + b, bf16 out; 16 rows x 128 cols per block ----
    const int blk  = blockIdx.x - nbBuild;
    const int wave = tid >> 6;
    const int lane = tid & 63;
    const int quad = lane >> 4;
    const int l16  = lane & 15;
    const int m0   = blk * 16;
    const int colbase = wave * 32;

    f32x4 acc0 = {0.f, 0.f, 0.f, 0.f};
    f32x4 acc1 = {0.f, 0.f, 0.f, 0.f};

    const float* xrow = x + (size_t)(m0 + l16) * N_IN + quad * 8;   // A: m=lane&15, k=quad*8+j
    const ushort_t* w0 = wb + (size_t)(colbase + l16) * N_IN + quad * 8;
    const ushort_t* w1 = w0 + 16 * N_IN;

    // hoist ALL x loads (16 x 16B per lane) so they pipeline against HBM latency
    float4 ax[16];
    #pragma unroll
    for (int t = 0; t < 8; t++) {
        ax[2 * t]     = *(const float4*)(xrow + t * 32);
        ax[2 * t + 1] = *(const float4*)(xrow + t * 32 + 4);
    }

    #pragma unroll
    for (int t = 0; t < 8; t++) {
        union { bf16x8 v; __hip_bfloat162 h2[4]; } u;
        u.h2[0] = __float22bfloat162_rn(make_float2(ax[2 * t].x, ax[2 * t].y));
        u.h2[1] = __float22bfloat162_rn(make_float2(ax[2 * t].z, ax[2 * t].w));
        u.h2[2] = __float22bfloat162_rn(make_float2(ax[2 * t + 1].x, ax[2 * t + 1].y));
        u.h2[3] = __float22bfloat162_rn(make_float2(ax[2 * t + 1].z, ax[2 * t + 1].w));
        bf16x8 bf0 = *(const bf16x8*)(w0 + t * 32);
        bf16x8 bf1 = *(const bf16x8*)(w1 + t * 32);
        acc0 = __builtin_amdgcn_mfma_f32_16x16x32_bf16(u.v, bf0, acc0, 0, 0, 0);
        acc1 = __builtin_amdgcn_mfma_f32_16x16x32_bf16(u.v, bf1, acc1, 0, 0, 0);
    }

    // C/D: row = quad*4 + reg, col = lane&15
    const int c0 = colbase + l16;
    const int c1 = c0 + 16;
    const float bv0 = b[c0];
    const float bv1 = b[c1];
    ushort_t* hp = h16 + (size_t)(m0 + quad * 4) * N_OUTC;
    #pragma unroll
    for (int r = 0; r < 4; r++) {
        hp[(size_t)r * N_OUTC + c0] = f2bf(acc0[r] + bv0);
        hp[(size_t)r * N_OUTC + c1] = f2bf(acc1[r] + bv1);
    }
}

// ---------------- SpMM via LDS accumulation: one block per 64-row superbin ----------------
// No sort/CSR needed: edges within a bin are unordered; fp32 accumulation happens in
// a 32KB LDS tile with LDS atomics. acc layout de-interleaved (col 2l -> slot l,
// col 2l+1 -> slot 64+l) so each ds_add hits banks 2-way (free).
__global__ __launch_bounds__(256) void spmm_lds_kernel(const ushort_t* __restrict__ h16,
                                                       const int* __restrict__ sbCount,
                                                       const int2* __restrict__ sbList, int sbCap,
                                                       const int* __restrict__ prev,
                                                       float* __restrict__ out, int Ndst) {
    __shared__ float acc[RPS * 128];
    const int tid  = threadIdx.x;
    const int wid  = tid >> 6;
    const int lane = tid & 63;
    const int sb   = blockIdx.x;

    #pragma unroll
    for (int i = 0; i < RPS * 128 / 256; i++) acc[tid + i * 256] = 0.f;
    __syncthreads();

    int cnt = sbCount[sb]; if (cnt > sbCap) cnt = sbCap;
    const int2* bk = sbList + (size_t)sb * sbCap;

    // each wave takes a contiguous quarter of the bin
    const int per = (cnt + 3) >> 2;
    const int lo = wid * per;
    int hi = lo + per; if (hi > cnt) hi = cnt;

    for (int bse = lo; bse < hi; bse += 64) {
        int idx = bse + lane;
        int2 my = make_int2(0, 0);             // pad: v=0 -> zero contribution
        if (idx < hi) my = bk[idx];
        int m = hi - bse; if (m > 64) m = 64;
        int mg = (m + 7) & ~7;
        for (int j = 0; j < mg; j += 8) {
            int x0 = __shfl(my.x, j + 0), x1 = __shfl(my.x, j + 1);
            int x2 = __shfl(my.x, j + 2), x3 = __shfl(my.x, j + 3);
            int x4 = __shfl(my.x, j + 4), x5 = __shfl(my.x, j + 5);
            int x6 = __shfl(my.x, j + 6), x7 = __shfl(my.x, j + 7);
            uint_t g0 = *(const uint_t*)(h16 + (size_t)(x0 & 0x1FFFF) * N_OUTC + 2 * lane);
            uint_t g1 = *(const uint_t*)(h16 + (size_t)(x1 & 0x1FFFF) * N_OUTC + 2 * lane);
            uint_t g2 = *(const uint_t*)(h16 + (size_t)(x2 & 0x1FFFF) * N_OUTC + 2 * lane);
            uint_t g3 = *(const uint_t*)(h16 + (size_t)(x3 & 0x1FFFF) * N_OUTC + 2 * lane);
            uint_t g4 = *(const uint_t*)(h16 + (size_t)(x4 & 0x1FFFF) * N_OUTC + 2 * lane);
            uint_t g5 = *(const uint_t*)(h16 + (size_t)(x5 & 0x1FFFF) * N_OUTC + 2 * lane);
            uint_t g6 = *(const uint_t*)(h16 + (size_t)(x6 & 0x1FFFF) * N_OUTC + 2 * lane);
            uint_t g7 = *(const uint_t*)(h16 + (size_t)(x7 & 0x1FFFF) * N_OUTC + 2 * lane);
            float v0 = __int_as_float(__shfl(my.y, j + 0));
            float v1 = __int_as_float(__shfl(my.y, j + 1));
            float v2 = __int_as_float(__shfl(my.y, j + 2));
            float v3 = __int_as_float(__shfl(my.y, j + 3));
            float v4 = __int_as_float(__shfl(my.y, j + 4));
            float v5 = __int_as_float(__shfl(my.y, j + 5));
            float v6 = __int_as_float(__shfl(my.y, j + 6));
            float v7 = __int_as_float(__shfl(my.y, j + 7));
            int r0 = (x0 >> 17) & 63, r1 = (x1 >> 17) & 63, r2 = (x2 >> 17) & 63, r3 = (x3 >> 17) & 63;
            int r4 = (x4 >> 17) & 63, r5 = (x5 >> 17) & 63, r6 = (x6 >> 17) & 63, r7 = (x7 >> 17) & 63;
            atomicAdd(&acc[r0 * 128 + lane],      v0 * bf_lo(g0));
            atomicAdd(&acc[r0 * 128 + 64 + lane], v0 * bf_hi(g0));
            atomicAdd(&acc[r1 * 128 + lane],      v1 * bf_lo(g1));
            atomicAdd(&acc[r1 * 128 + 64 + lane], v1 * bf_hi(g1));
            atomicAdd(&acc[r2 * 128 + lane],      v2 * bf_lo(g2));
            atomicAdd(&acc[r2 * 128 + 64 + lane], v2 * bf_hi(g2));
            atomicAdd(&acc[r3 * 128 + lane],      v3 * bf_lo(g3));
            atomicAdd(&acc[r3 * 128 + 64 + lane], v3 * bf_hi(g3));
            atomicAdd(&acc[r4 * 128 + lane],      v4 * bf_lo(g4));
            atomicAdd(&acc[r4 * 128 + 64 + lane], v4 * bf_hi(g4));
            atomicAdd(&acc[r5 * 128 + lane],      v5 * bf_lo(g5));
            atomicAdd(&acc[r5 * 128 + 64 + lane], v5 * bf_hi(g5));
            atomicAdd(&acc[r6 * 128 + lane],      v6 * bf_lo(g6));
            atomicAdd(&acc[r6 * 128 + 64 + lane], v6 * bf_hi(g6));
            atomicAdd(&acc[r7 * 128 + lane],      v7 * bf_lo(g7));
            atomicAdd(&acc[r7 * 128 + 64 + lane], v7 * bf_hi(g7));
        }
    }
    __syncthreads();

    // writeout: concat h[prev[R]] (cols 0..127) + support (cols 128..255)
    for (int r = wid; r < RPS; r += 4) {
        int R = sb * RPS + r;
        if (R >= Ndst) break;
        uint_t g = *(const uint_t*)(h16 + (size_t)prev[R] * N_OUTC + 2 * lane);
        float2* o = (float2*)(out + (size_t)R * 256);
        o[lane]      = make_float2(bf_lo(g), bf_hi(g));
        o[64 + lane] = make_float2(acc[r * 128 + lane], acc[r * 128 + 64 + lane]);
    }
}

// ---------------- spill fixup (expected empty) ----------------
__global__ void spill_kernel(const ushort_t* __restrict__ h16, const int4* __restrict__ spill,
                             const int* __restrict__ spillCnt, float* __restrict__ out) {
    int n = *spillCnt; if (n > SPILL_CAP) n = SPILL_CAP;
    int total = n * 64;
    for (int t = blockIdx.x * blockDim.x + threadIdx.x; t < total; t += gridDim.x * blockDim.x) {
        int idx = t >> 6, lane = t & 63;
        int4 s = spill[idx];
        uint_t g = *(const uint_t*)(h16 + (size_t)s.y * N_OUTC + 2 * lane);
        float v = __int_as_float(s.z);
        atomicAdd(&out[(size_t)s.x * 256 + 128 + 2 * lane],     v * bf_lo(g));
        atomicAdd(&out[(size_t)s.x * 256 + 128 + 2 * lane + 1], v * bf_hi(g));
    }
}

// ---------------- fallback path (ws too small; not expected) ----------------
__global__ __launch_bounds__(256) void gemm_only_kernel(const float* __restrict__ x,
                                                        const ushort_t* __restrict__ wb,
                                                        const float* __restrict__ b,
                                                        ushort_t* __restrict__ h16) {
    const int tid  = threadIdx.x;
    const int wave = tid >> 6;
    const int lane = tid & 63;
    const int quad = lane >> 4;
    const int l16  = lane & 15;
    const int m0   = blockIdx.x * 16;
    const int colbase = wave * 32;
    f32x4 acc0 = {0.f, 0.f, 0.f, 0.f};
    f32x4 acc1 = {0.f, 0.f, 0.f, 0.f};
    const float* xrow = x + (size_t)(m0 + l16) * N_IN + quad * 8;
    const ushort_t* w0 = wb + (size_t)(colbase + l16) * N_IN + quad * 8;
    const ushort_t* w1 = w0 + 16 * N_IN;
    #pragma unroll
    for (int kb = 0; kb < N_IN; kb += 32) {
        float4 a0 = *(const float4*)(xrow + kb);
        float4 a1 = *(const float4*)(xrow + kb + 4);
        union { bf16x8 v; __hip_bfloat162 h2[4]; } u;
        u.h2[0] = __float22bfloat162_rn(make_float2(a0.x, a0.y));
        u.h2[1] = __float22bfloat162_rn(make_float2(a0.z, a0.w));
        u.h2[2] = __float22bfloat162_rn(make_float2(a1.x, a1.y));
        u.h2[3] = __float22bfloat162_rn(make_float2(a1.z, a1.w));
        bf16x8 bf0 = *(const bf16x8*)(w0 + kb);
        bf16x8 bf1 = *(const bf16x8*)(w1 + kb);
        acc0 = __builtin_amdgcn_mfma_f32_16x16x32_bf16(u.v, bf0, acc0, 0, 0, 0);
        acc1 = __builtin_amdgcn_mfma_f32_16x16x32_bf16(u.v, bf1, acc1, 0, 0, 0);
    }
    const int c0 = colbase + l16;
    const int c1 = c0 + 16;
    const float bv0 = b[c0];
    const float bv1 = b[c1];
    ushort_t* hp = h16 + (size_t)(m0 + quad * 4) * N_OUTC;
    #pragma unroll
    for (int r = 0; r < 4; r++) {
        hp[(size_t)r * N_OUTC + c0] = f2bf(acc0[r] + bv0);
        hp[(size_t)r * N_OUTC + c1] = f2bf(acc1[r] + bv1);
    }
}

__global__ void concat_only_kernel(const ushort_t* __restrict__ h16, const int* __restrict__ prev,
                                   float* __restrict__ out, int Ndst) {
    int t = blockIdx.x * blockDim.x + threadIdx.x;
    int r = t >> 6, lane = t & 63;
    if (r >= Ndst) return;
    uint_t g = *(const uint_t*)(h16 + (size_t)prev[r] * N_OUTC + 2 * lane);
    ((float2*)out)[(size_t)r * 128 + lane] = make_float2(bf_lo(g), bf_hi(g));
}

__global__ void spmm_atomic_kernel(const ushort_t* __restrict__ h16, const int* __restrict__ rows,
                                   const int* __restrict__ cols, const float* __restrict__ vals,
                                   int E, float* __restrict__ out) {
    long long t = (long long)blockIdx.x * blockDim.x + threadIdx.x;
    int e = (int)(t >> 6), lane = (int)(t & 63);
    if (e >= E) return;
    uint_t g = *(const uint_t*)(h16 + (size_t)cols[e] * N_OUTC + 2 * lane);
    float v = vals[e];
    int r = rows[e];
    atomicAdd(&out[(size_t)r * 256 + 128 + 2 * lane],     v * bf_lo(g));
    atomicAdd(&out[(size_t)r * 256 + 128 + 2 * lane + 1], v * bf_hi(g));
}

extern "C" void kernel_launch(void* const* d_in, const int* in_sizes, int n_in,
                              void* d_out, int out_size, void* d_ws, size_t ws_size,
                              hipStream_t stream) {
    const float* x    = (const float*)d_in[0];
    const float* W    = (const float*)d_in[1];
    const float* b    = (const float*)d_in[2];
    const float* vals = (const float*)d_in[3];
    const int*   rows = (const int*)d_in[4];
    const int*   cols = (const int*)d_in[5];
    const int*   prev = (const int*)d_in[6];
    float* out = (float*)d_out;

    const int Nsrc = in_sizes[0] / N_IN;   // 100000
    const int E    = in_sizes[3];          // 3200000
    const int Ndst = in_sizes[6];          // 50000
    const int NSB  = (Ndst + RPS - 1) / RPS;           // 782
    const int sbCap = E / NSB + 516;                   // mean ~4092 + 8 sigma
    const int nbBuild = (E + TILE - 1) / TILE;         // 782
    const int gemmBlocks = Nsrc / 16;                  // 6250

    char* ws = (char*)d_ws;
    size_t off = 0;
    ushort_t* h16 = (ushort_t*)(ws + off);
    off += (size_t)Nsrc * N_OUTC * sizeof(ushort_t);               // 25.6 MB
    ushort_t* wb = (ushort_t*)(ws + off);
    off += (size_t)N_OUTC * N_IN * sizeof(ushort_t);               // 64 KB
    off = (off + 255) & ~(size_t)255;
    int* sbCount  = (int*)(ws + off);                               // memset zone: NSB + 1
    int* spillCnt = sbCount + NSB;
    size_t memsetBytes = ((size_t)NSB + 1) * sizeof(int);
    off += memsetBytes;
    off = (off + 255) & ~(size_t)255;
    int4* spill = (int4*)(ws + off);
    off += (size_t)SPILL_CAP * sizeof(int4);
    off = (off + 255) & ~(size_t)255;
    int2* sbList = (int2*)(ws + off);
    off += (size_t)NSB * sbCap * sizeof(int2);                     // ~28.8 MB

    cvtW_kernel<<<(N_OUTC * N_IN + 255) / 256, 256, 0, stream>>>(W, wb, N_OUTC * N_IN);

    if (off <= ws_size && NSB <= NSB_MAX) {
        hipMemsetAsync(sbCount, 0, memsetBytes, stream);
        fused_build_gemm_kernel<<<nbBuild + gemmBlocks, 256, 0, stream>>>(
            rows, cols, vals, E, sbCount, sbList, sbCap, NSB, spillCnt, spill, nbBuild,
            x, wb, b, h16);
        spmm_lds_kernel<<<NSB, 256, 0, stream>>>(h16, sbCount, sbList, sbCap, prev, out, Ndst);
        spill_kernel<<<64, 256, 0, stream>>>(h16, spill, spillCnt, out);
    } else {
        gemm_only_kernel<<<gemmBlocks, 256, 0, stream>>>(x, wb, b, h16);
        hipMemsetAsync(out, 0, (size_t)out_size * sizeof(float), stream);
        concat_only_kernel<<<((size_t)Ndst * 64 + 255) / 256, 256, 0, stream>>>(h16, prev, out, Ndst);
        spmm_atomic_kernel<<<((size_t)E * 64 + 255) / 256, 256, 0, stream>>>(h16, rows, cols, vals, E, out);
    }
}

// Round 5
// 476.575 us; speedup vs baseline: 6.4418x; 6.4418x over previous
//
#include <hip/hip_runtime.h>
#include <hip/hip_bf16.h>

#define N_IN      256
#define N_OUTC    128
#define RPS       64       // rows per superbin
#define RPS_SHIFT 6
#define NSB_MAX   1024
#define TILE      4096     // edges per build block
#define EPT       16       // edges per thread in build
#define SPILL_CAP 8192

typedef __attribute__((ext_vector_type(8))) short bf16x8;
typedef __attribute__((ext_vector_type(4))) float f32x4;
typedef unsigned short ushort_t;
typedef unsigned int uint_t;

__device__ inline unsigned short f2bf(float f) {
    unsigned u = __float_as_uint(f);
    unsigned r = u + 0x7fffu + ((u >> 16) & 1u);
    return (unsigned short)(r >> 16);
}
__device__ inline float bf_lo(uint_t g) { return __uint_as_float(g << 16); }
__device__ inline float bf_hi(uint_t g) { return __uint_as_float(g & 0xFFFF0000u); }

// ---------------- W fp32 [128,256] -> bf16 ----------------
__global__ void cvtW_kernel(const float* __restrict__ W, ushort_t* __restrict__ wb, int n) {
    int i = blockIdx.x * blockDim.x + threadIdx.x;
    if (i < n) wb[i] = f2bf(W[i]);
}

// ---------------- fused: buildA (blocks [0,nbBuild)) + gemm (rest) ----------------
// build: LDS-ranked superbin binning. Register discipline: only ONE packed int per
// edge (sb<<13 | rank, 16 VGPRs) stays live across the barriers; phase 3 re-reads
// rows/cols/vals from global (coalesced, L2-hot) instead of spilling 64 ints/lane
// to scratch (round-0's hidden ~70MB WRITE_SIZE component at VGPR_Count=44).
__global__ __launch_bounds__(256) void fused_build_gemm_kernel(
        // build args
        const int* __restrict__ rows, const int* __restrict__ cols,
        const float* __restrict__ vals, int E,
        int* __restrict__ sbCount, int2* __restrict__ sbList, int sbCap, int nsb,
        int* __restrict__ spillCnt, int4* __restrict__ spill, int nbBuild,
        // gemm args
        const float* __restrict__ x, const ushort_t* __restrict__ wb,
        const float* __restrict__ b, ushort_t* __restrict__ h16) {
    __shared__ int cur[NSB_MAX];
    __shared__ int gbase[NSB_MAX];
    const int tid = threadIdx.x;

    if (blockIdx.x < (uint_t)nbBuild) {
        // ---- buildA: LDS-ranked superbin binning, coalesced-run writes ----
        const int base = blockIdx.x * TILE;
        for (int i = tid; i < nsb; i += 256) cur[i] = 0;
        __syncthreads();

        // phase 1: rank each edge within (block, superbin). rank < TILE=4096 fits 13 bits.
        int comb[EPT];
        #pragma unroll
        for (int k = 0; k < EPT; k++) {
            int e = base + tid + k * 256;
            comb[k] = -1;
            if (e < E) {
                int sb = rows[e] >> RPS_SHIFT;
                int rk = atomicAdd(&cur[sb], 1);
                comb[k] = (sb << 13) | rk;
            }
        }
        __syncthreads();

        // phase 2: one global atomic per (block, bin)
        for (int i = tid; i < nsb; i += 256)
            gbase[i] = cur[i] ? atomicAdd(&sbCount[i], cur[i]) : 0;
        __syncthreads();

        // phase 3: re-read edge data (L2-hot) and place at gbase+rank
        #pragma unroll
        for (int k = 0; k < EPT; k++) {
            if (comb[k] < 0) continue;
            int e  = base + tid + k * 256;
            int sb = ((uint_t)comb[k]) >> 13;
            int rk = comb[k] & 0x1FFF;
            int r = rows[e], c = cols[e];
            int ev = __float_as_int(vals[e]);
            int pos = gbase[sb] + rk;
            if (pos < sbCap) {
                sbList[(size_t)sb * sbCap + pos] = make_int2(c | ((r & (RPS - 1)) << 17), ev);
            } else {
                int sp = atomicAdd(spillCnt, 1);
                if (sp < SPILL_CAP)
                    spill[sp] = make_int4(r, c, ev, 0);
            }
        }
        return;
    }

    // ---- gemm: h = x @ W^T + b, bf16 out (identical to the 437us-verified version) ----
    const int blk  = blockIdx.x - nbBuild;
    const int wave = tid >> 6;
    const int lane = tid & 63;
    const int quad = lane >> 4;
    const int l16  = lane & 15;
    const int m0   = blk * 16;
    const int colbase = wave * 32;

    f32x4 acc0 = {0.f, 0.f, 0.f, 0.f};
    f32x4 acc1 = {0.f, 0.f, 0.f, 0.f};

    const float* xrow = x + (size_t)(m0 + l16) * N_IN + quad * 8;   // A: m=lane&15, k=quad*8+j
    const ushort_t* w0 = wb + (size_t)(colbase + l16) * N_IN + quad * 8;
    const ushort_t* w1 = w0 + 16 * N_IN;

    #pragma unroll
    for (int kb = 0; kb < N_IN; kb += 32) {
        float4 a0 = *(const float4*)(xrow + kb);
        float4 a1 = *(const float4*)(xrow + kb + 4);
        union { bf16x8 v; __hip_bfloat162 h2[4]; } u;
        u.h2[0] = __float22bfloat162_rn(make_float2(a0.x, a0.y));
        u.h2[1] = __float22bfloat162_rn(make_float2(a0.z, a0.w));
        u.h2[2] = __float22bfloat162_rn(make_float2(a1.x, a1.y));
        u.h2[3] = __float22bfloat162_rn(make_float2(a1.z, a1.w));
        bf16x8 bf0 = *(const bf16x8*)(w0 + kb);
        bf16x8 bf1 = *(const bf16x8*)(w1 + kb);
        acc0 = __builtin_amdgcn_mfma_f32_16x16x32_bf16(u.v, bf0, acc0, 0, 0, 0);
        acc1 = __builtin_amdgcn_mfma_f32_16x16x32_bf16(u.v, bf1, acc1, 0, 0, 0);
    }

    // C/D: row = quad*4 + reg, col = lane&15
    const int c0 = colbase + l16;
    const int c1 = c0 + 16;
    const float bv0 = b[c0];
    const float bv1 = b[c1];
    ushort_t* hp = h16 + (size_t)(m0 + quad * 4) * N_OUTC;
    #pragma unroll
    for (int r = 0; r < 4; r++) {
        hp[(size_t)r * N_OUTC + c0] = f2bf(acc0[r] + bv0);
        hp[(size_t)r * N_OUTC + c1] = f2bf(acc1[r] + bv1);
    }
}

// ---------------- exclusive scan of clamped superbin totals (1 block, 1024 thr) ----------------
__global__ __launch_bounds__(1024) void sbscan_kernel(const int* __restrict__ sbCount, int sbCap,
                                                      int* __restrict__ sbBase, int nsb) {
    __shared__ int a[NSB_MAX], bsh[NSB_MAX];
    int tid = threadIdx.x;
    int v = 0;
    if (tid < nsb) { v = sbCount[tid]; if (v > sbCap) v = sbCap; }
    a[tid] = v; __syncthreads();
    int* src = a; int* dst = bsh;
    for (int off = 1; off < 1024; off <<= 1) {
        dst[tid] = src[tid] + ((tid >= off) ? src[tid - off] : 0);
        __syncthreads();
        int* t = src; src = dst; dst = t;
    }
    if (tid < nsb) sbBase[tid] = tid ? src[tid - 1] : 0;
}

// ---------------- sort: superbin list -> CSR (in-L2 counting sort, 64 rows/sb) ----------------
__global__ __launch_bounds__(256) void sort_kernel(const int* __restrict__ sbCount,
                                                   const int* __restrict__ sbBase,
                                                   const int2* __restrict__ sbList, int sbCap,
                                                   int2* __restrict__ csr,
                                                   int* __restrict__ rowStart, int* __restrict__ rowCnt,
                                                   int Ndst) {
    __shared__ int hist[RPS];
    __shared__ int scanA[RPS];
    __shared__ int curx[RPS];
    const int sb  = blockIdx.x;
    const int tid = threadIdx.x;
    int len = sbCount[sb]; if (len > sbCap) len = sbCap;
    const int base = sbBase[sb];
    const int2* lp = sbList + (size_t)sb * sbCap;

    if (tid < RPS) hist[tid] = 0;
    __syncthreads();

    // phase 1: histogram (4-deep prefetch)
    int i = tid;
    for (; i + 768 < len; i += 1024) {
        int x0 = lp[i].x, x1 = lp[i + 256].x, x2 = lp[i + 512].x, x3 = lp[i + 768].x;
        atomicAdd(&hist[((uint_t)x0) >> 17], 1);
        atomicAdd(&hist[((uint_t)x1) >> 17], 1);
        atomicAdd(&hist[((uint_t)x2) >> 17], 1);
        atomicAdd(&hist[((uint_t)x3) >> 17], 1);
    }
    for (; i < len; i += 256) atomicAdd(&hist[((uint_t)lp[i].x) >> 17], 1);
    __syncthreads();

    // phase 2: inclusive scan over 64 rows (predicated Hillis-Steele)
    if (tid < RPS) scanA[tid] = hist[tid];
    __syncthreads();
    for (int off = 1; off < RPS; off <<= 1) {
        int t = 0;
        if (tid < RPS) t = scanA[tid] + ((tid >= off) ? scanA[tid - off] : 0);
        __syncthreads();
        if (tid < RPS) scanA[tid] = t;
        __syncthreads();
    }
    if (tid < RPS) {
        int excl = tid ? scanA[tid - 1] : 0;
        curx[tid] = excl;
        int r = sb * RPS + tid;
        if (r < Ndst) { rowStart[r] = base + excl; rowCnt[r] = hist[tid]; }
    }
    __syncthreads();

    // phase 3: scatter (4-deep prefetch); writes stay within this sb's CSR span (L2-resident)
    i = tid;
    for (; i + 768 < len; i += 1024) {
        int2 e0 = lp[i], e1 = lp[i + 256], e2 = lp[i + 512], e3 = lp[i + 768];
        int p0 = atomicAdd(&curx[((uint_t)e0.x) >> 17], 1);
        int p1 = atomicAdd(&curx[((uint_t)e1.x) >> 17], 1);
        int p2 = atomicAdd(&curx[((uint_t)e2.x) >> 17], 1);
        int p3 = atomicAdd(&curx[((uint_t)e3.x) >> 17], 1);
        csr[(size_t)base + p0] = make_int2(e0.x & 0x1FFFF, e0.y);
        csr[(size_t)base + p1] = make_int2(e1.x & 0x1FFFF, e1.y);
        csr[(size_t)base + p2] = make_int2(e2.x & 0x1FFFF, e2.y);
        csr[(size_t)base + p3] = make_int2(e3.x & 0x1FFFF, e3.y);
    }
    for (; i < len; i += 256) {
        int2 e = lp[i];
        int pos = atomicAdd(&curx[((uint_t)e.x) >> 17], 1);
        csr[(size_t)base + pos] = make_int2(e.x & 0x1FFFF, e.y);
    }
}

// ---------------- SpMM: wave per dst row, coalesced edge loads + shfl broadcast ----------------
__global__ __launch_bounds__(256) void spmm_concat_kernel(const ushort_t* __restrict__ h16,
                                                          const int* __restrict__ rowStart,
                                                          const int* __restrict__ rowCnt,
                                                          const int2* __restrict__ csr,
                                                          const int* __restrict__ prev,
                                                          float* __restrict__ out, int Ndst) {
    int r = blockIdx.x * 4 + (threadIdx.x >> 6);
    if (r >= Ndst) return;
    const int lane = threadIdx.x & 63;
    const int cnt = rowCnt[r];
    const int2* bk = csr + rowStart[r];

    float2 acc = {0.f, 0.f};
    for (int bse = 0; bse < cnt; bse += 64) {
        int idx = bse + lane;
        int2 my = make_int2(0, 0);             // pad: v=0 -> zero contribution, c=0 safe
        if (idx < cnt) my = bk[idx];
        int m = cnt - bse; if (m > 64) m = 64;
        int mg = (m + 7) & ~7;
        for (int j = 0; j < mg; j += 8) {
            int c0 = __shfl(my.x, j + 0), c1 = __shfl(my.x, j + 1);
            int c2 = __shfl(my.x, j + 2), c3 = __shfl(my.x, j + 3);
            int c4 = __shfl(my.x, j + 4), c5 = __shfl(my.x, j + 5);
            int c6 = __shfl(my.x, j + 6), c7 = __shfl(my.x, j + 7);
            uint_t g0 = *(const uint_t*)(h16 + (size_t)c0 * N_OUTC + 2 * lane);
            uint_t g1 = *(const uint_t*)(h16 + (size_t)c1 * N_OUTC + 2 * lane);
            uint_t g2 = *(const uint_t*)(h16 + (size_t)c2 * N_OUTC + 2 * lane);
            uint_t g3 = *(const uint_t*)(h16 + (size_t)c3 * N_OUTC + 2 * lane);
            uint_t g4 = *(const uint_t*)(h16 + (size_t)c4 * N_OUTC + 2 * lane);
            uint_t g5 = *(const uint_t*)(h16 + (size_t)c5 * N_OUTC + 2 * lane);
            uint_t g6 = *(const uint_t*)(h16 + (size_t)c6 * N_OUTC + 2 * lane);
            uint_t g7 = *(const uint_t*)(h16 + (size_t)c7 * N_OUTC + 2 * lane);
            float v0 = __int_as_float(__shfl(my.y, j + 0));
            float v1 = __int_as_float(__shfl(my.y, j + 1));
            float v2 = __int_as_float(__shfl(my.y, j + 2));
            float v3 = __int_as_float(__shfl(my.y, j + 3));
            float v4 = __int_as_float(__shfl(my.y, j + 4));
            float v5 = __int_as_float(__shfl(my.y, j + 5));
            float v6 = __int_as_float(__shfl(my.y, j + 6));
            float v7 = __int_as_float(__shfl(my.y, j + 7));
            acc.x += v0 * bf_lo(g0); acc.y += v0 * bf_hi(g0);
            acc.x += v1 * bf_lo(g1); acc.y += v1 * bf_hi(g1);
            acc.x += v2 * bf_lo(g2); acc.y += v2 * bf_hi(g2);
            acc.x += v3 * bf_lo(g3); acc.y += v3 * bf_hi(g3);
            acc.x += v4 * bf_lo(g4); acc.y += v4 * bf_hi(g4);
            acc.x += v5 * bf_lo(g5); acc.y += v5 * bf_hi(g5);
            acc.x += v6 * bf_lo(g6); acc.y += v6 * bf_hi(g6);
            acc.x += v7 * bf_lo(g7); acc.y += v7 * bf_hi(g7);
        }
    }

    int p = prev[r];
    uint_t g = *(const uint_t*)(h16 + (size_t)p * N_OUTC + 2 * lane);
    float2* o = (float2*)(out + (size_t)r * 256);
    o[lane]      = make_float2(bf_lo(g), bf_hi(g));
    o[64 + lane] = make_float2(acc.x, acc.y);
}

// ---------------- spill fixup (expected empty) ----------------
__global__ void spill_kernel(const ushort_t* __restrict__ h16, const int4* __restrict__ spill,
                             const int* __restrict__ spillCnt, float* __restrict__ out) {
    int n = *spillCnt; if (n > SPILL_CAP) n = SPILL_CAP;
    int total = n * 64;
    for (int t = blockIdx.x * blockDim.x + threadIdx.x; t < total; t += gridDim.x * blockDim.x) {
        int idx = t >> 6, lane = t & 63;
        int4 s = spill[idx];
        uint_t g = *(const uint_t*)(h16 + (size_t)s.y * N_OUTC + 2 * lane);
        float v = __int_as_float(s.z);
        atomicAdd(&out[(size_t)s.x * 256 + 128 + 2 * lane],     v * bf_lo(g));
        atomicAdd(&out[(size_t)s.x * 256 + 128 + 2 * lane + 1], v * bf_hi(g));
    }
}

// ---------------- fallback path (ws too small; not expected) ----------------
__global__ __launch_bounds__(256) void gemm_only_kernel(const float* __restrict__ x,
                                                        const ushort_t* __restrict__ wb,
                                                        const float* __restrict__ b,
                                                        ushort_t* __restrict__ h16) {
    const int tid  = threadIdx.x;
    const int wave = tid >> 6;
    const int lane = tid & 63;
    const int quad = lane >> 4;
    const int l16  = lane & 15;
    const int m0   = blockIdx.x * 16;
    const int colbase = wave * 32;
    f32x4 acc0 = {0.f, 0.f, 0.f, 0.f};
    f32x4 acc1 = {0.f, 0.f, 0.f, 0.f};
    const float* xrow = x + (size_t)(m0 + l16) * N_IN + quad * 8;
    const ushort_t* w0 = wb + (size_t)(colbase + l16) * N_IN + quad * 8;
    const ushort_t* w1 = w0 + 16 * N_IN;
    #pragma unroll
    for (int kb = 0; kb < N_IN; kb += 32) {
        float4 a0 = *(const float4*)(xrow + kb);
        float4 a1 = *(const float4*)(xrow + kb + 4);
        union { bf16x8 v; __hip_bfloat162 h2[4]; } u;
        u.h2[0] = __float22bfloat162_rn(make_float2(a0.x, a0.y));
        u.h2[1] = __float22bfloat162_rn(make_float2(a0.z, a0.w));
        u.h2[2] = __float22bfloat162_rn(make_float2(a1.x, a1.y));
        u.h2[3] = __float22bfloat162_rn(make_float2(a1.z, a1.w));
        bf16x8 bf0 = *(const bf16x8*)(w0 + kb);
        bf16x8 bf1 = *(const bf16x8*)(w1 + kb);
        acc0 = __builtin_amdgcn_mfma_f32_16x16x32_bf16(u.v, bf0, acc0, 0, 0, 0);
        acc1 = __builtin_amdgcn_mfma_f32_16x16x32_bf16(u.v, bf1, acc1, 0, 0, 0);
    }
    const int c0 = colbase + l16;
    const int c1 = c0 + 16;
    const float bv0 = b[c0];
    const float bv1 = b[c1];
    ushort_t* hp = h16 + (size_t)(m0 + quad * 4) * N_OUTC;
    #pragma unroll
    for (int r = 0; r < 4; r++) {
        hp[(size_t)r * N_OUTC + c0] = f2bf(acc0[r] + bv0);
        hp[(size_t)r * N_OUTC + c1] = f2bf(acc1[r] + bv1);
    }
}

__global__ void concat_only_kernel(const ushort_t* __restrict__ h16, const int* __restrict__ prev,
                                   float* __restrict__ out, int Ndst) {
    int t = blockIdx.x * blockDim.x + threadIdx.x;
    int r = t >> 6, lane = t & 63;
    if (r >= Ndst) return;
    uint_t g = *(const uint_t*)(h16 + (size_t)prev[r] * N_OUTC + 2 * lane);
    ((float2*)out)[(size_t)r * 128 + lane] = make_float2(bf_lo(g), bf_hi(g));
}

__global__ void spmm_atomic_kernel(const ushort_t* __restrict__ h16, const int* __restrict__ rows,
                                   const int* __restrict__ cols, const float* __restrict__ vals,
                                   int E, float* __restrict__ out) {
    long long t = (long long)blockIdx.x * blockDim.x + threadIdx.x;
    int e = (int)(t >> 6), lane = (int)(t & 63);
    if (e >= E) return;
    uint_t g = *(const uint_t*)(h16 + (size_t)cols[e] * N_OUTC + 2 * lane);
    float v = vals[e];
    int r = rows[e];
    atomicAdd(&out[(size_t)r * 256 + 128 + 2 * lane],     v * bf_lo(g));
    atomicAdd(&out[(size_t)r * 256 + 128 + 2 * lane + 1], v * bf_hi(g));
}

extern "C" void kernel_launch(void* const* d_in, const int* in_sizes, int n_in,
                              void* d_out, int out_size, void* d_ws, size_t ws_size,
                              hipStream_t stream) {
    const float* x    = (const float*)d_in[0];
    const float* W    = (const float*)d_in[1];
    const float* b    = (const float*)d_in[2];
    const float* vals = (const float*)d_in[3];
    const int*   rows = (const int*)d_in[4];
    const int*   cols = (const int*)d_in[5];
    const int*   prev = (const int*)d_in[6];
    float* out = (float*)d_out;

    const int Nsrc = in_sizes[0] / N_IN;   // 100000
    const int E    = in_sizes[3];          // 3200000
    const int Ndst = in_sizes[6];          // 50000
    const int NSB  = (Ndst + RPS - 1) / RPS;           // 782
    const int sbCap = E / NSB + 516;                   // mean ~4092 + 8 sigma
    const int nbBuild = (E + TILE - 1) / TILE;         // 782
    const int gemmBlocks = Nsrc / 16;                  // 6250

    char* ws = (char*)d_ws;
    size_t off = 0;
    ushort_t* h16 = (ushort_t*)(ws + off);
    off += (size_t)Nsrc * N_OUTC * sizeof(ushort_t);               // 25.6 MB
    ushort_t* wb = (ushort_t*)(ws + off);
    off += (size_t)N_OUTC * N_IN * sizeof(ushort_t);               // 64 KB
    off = (off + 255) & ~(size_t)255;
    int* sbCount  = (int*)(ws + off);                               // memset zone: NSB + 1
    int* spillCnt = sbCount + NSB;
    size_t memsetBytes = ((size_t)NSB + 1) * sizeof(int);
    off += memsetBytes;
    off = (off + 255) & ~(size_t)255;
    int* sbBase = (int*)(ws + off);
    off += (size_t)NSB * sizeof(int);
    off = (off + 255) & ~(size_t)255;
    int* rowStart = (int*)(ws + off);
    off += (size_t)Ndst * sizeof(int);
    int* rowCnt = (int*)(ws + off);
    off += (size_t)Ndst * sizeof(int);
    off = (off + 255) & ~(size_t)255;
    int4* spill = (int4*)(ws + off);
    off += (size_t)SPILL_CAP * sizeof(int4);
    off = (off + 255) & ~(size_t)255;
    int2* sbList = (int2*)(ws + off);
    off += (size_t)NSB * sbCap * sizeof(int2);                     // ~28.8 MB
    off = (off + 255) & ~(size_t)255;
    int2* csr = (int2*)(ws + off);
    off += (size_t)E * sizeof(int2);                               // 25.6 MB

    cvtW_kernel<<<(N_OUTC * N_IN + 255) / 256, 256, 0, stream>>>(W, wb, N_OUTC * N_IN);

    if (off <= ws_size && NSB <= NSB_MAX) {
        hipMemsetAsync(sbCount, 0, memsetBytes, stream);
        fused_build_gemm_kernel<<<nbBuild + gemmBlocks, 256, 0, stream>>>(
            rows, cols, vals, E, sbCount, sbList, sbCap, NSB, spillCnt, spill, nbBuild,
            x, wb, b, h16);
        sbscan_kernel<<<1, 1024, 0, stream>>>(sbCount, sbCap, sbBase, NSB);
        sort_kernel<<<NSB, 256, 0, stream>>>(sbCount, sbBase, sbList, sbCap,
                                             csr, rowStart, rowCnt, Ndst);
        spmm_concat_kernel<<<(Ndst + 3) / 4, 256, 0, stream>>>(h16, rowStart, rowCnt, csr,
                                                               prev, out, Ndst);
        spill_kernel<<<64, 256, 0, stream>>>(h16, spill, spillCnt, out);
    } else {
        gemm_only_kernel<<<gemmBlocks, 256, 0, stream>>>(x, wb, b, h16);
        hipMemsetAsync(out, 0, (size_t)out_size * sizeof(float), stream);
        concat_only_kernel<<<((size_t)Ndst * 64 + 255) / 256, 256, 0, stream>>>(h16, prev, out, Ndst);
        spmm_atomic_kernel<<<((size_t)E * 64 + 255) / 256, 256, 0, stream>>>(h16, rows, cols, vals, E, out);
    }
}

// Round 6
// 438.581 us; speedup vs baseline: 6.9998x; 1.0866x over previous
//
#include <hip/hip_runtime.h>
#include <hip/hip_bf16.h>

#define N_IN      256
#define N_OUTC    128
#define RPS       64       // rows per superbin
#define RPS_SHIFT 6
#define NSB_MAX   1024
#define TILE      4096     // edges per build block
#define EPT       16       // edges per thread in build
#define SPILL_CAP 8192

typedef __attribute__((ext_vector_type(8))) short bf16x8;
typedef __attribute__((ext_vector_type(4))) float f32x4;
typedef unsigned short ushort_t;
typedef unsigned int uint_t;

__device__ inline unsigned short f2bf(float f) {
    unsigned u = __float_as_uint(f);
    unsigned r = u + 0x7fffu + ((u >> 16) & 1u);
    return (unsigned short)(r >> 16);
}
__device__ inline float bf_lo(uint_t g) { return __uint_as_float(g << 16); }
__device__ inline float bf_hi(uint_t g) { return __uint_as_float(g & 0xFFFF0000u); }

// ---------------- W fp32 [128,256] -> bf16 ----------------
__global__ void cvtW_kernel(const float* __restrict__ W, ushort_t* __restrict__ wb, int n) {
    int i = blockIdx.x * blockDim.x + threadIdx.x;
    if (i < n) wb[i] = f2bf(W[i]);
}

// ---------------- fused: buildA (blocks [0,nbBuild)) + gemm (rest) ----------------
// build: round-0 verbatim (measured 160us config; the phase-3-reread variant was
// slower AND wrote more — r5 counters).
// gemm: __launch_bounds__(256,4) raises the compiler VGPR budget to 128 so the
// K-loop can hold ~6 x-loads in flight (x is L3-resident; ~450cy latency; 2-deep
// at VGPR<=64 was the measured 1.1 TB/s ceiling). Explicit 2-ahead x / 1-ahead w
// register pipeline gives the scheduler the shape to fill.
__global__ __launch_bounds__(256, 4) void fused_build_gemm_kernel(
        // build args
        const int* __restrict__ rows, const int* __restrict__ cols,
        const float* __restrict__ vals, int E,
        int* __restrict__ sbCount, int2* __restrict__ sbList, int sbCap, int nsb,
        int* __restrict__ spillCnt, int4* __restrict__ spill, int nbBuild,
        // gemm args
        const float* __restrict__ x, const ushort_t* __restrict__ wb,
        const float* __restrict__ b, ushort_t* __restrict__ h16) {
    __shared__ int cur[NSB_MAX];
    __shared__ int gbase[NSB_MAX];
    const int tid = threadIdx.x;

    if (blockIdx.x < (uint_t)nbBuild) {
        // ---- buildA: LDS-ranked superbin binning, coalesced-run writes ----
        const int base = blockIdx.x * TILE;
        for (int i = tid; i < nsb; i += 256) cur[i] = 0;
        __syncthreads();

        int ex[EPT], evb[EPT], esb[EPT], erk[EPT];
        #pragma unroll
        for (int k = 0; k < EPT; k++) {
            int e = base + tid + k * 256;
            if (e < E) {
                int r = rows[e], c = cols[e];
                evb[k] = __float_as_int(vals[e]);
                esb[k] = r >> RPS_SHIFT;
                ex[k]  = c | ((r & (RPS - 1)) << 17);
                erk[k] = atomicAdd(&cur[esb[k]], 1);
            } else esb[k] = -1;
        }
        __syncthreads();
        for (int i = tid; i < nsb; i += 256)
            gbase[i] = cur[i] ? atomicAdd(&sbCount[i], cur[i]) : 0;
        __syncthreads();

        #pragma unroll
        for (int k = 0; k < EPT; k++) {
            if (esb[k] < 0) continue;
            int pos = gbase[esb[k]] + erk[k];
            if (pos < sbCap) {
                sbList[(size_t)esb[k] * sbCap + pos] = make_int2(ex[k], evb[k]);
            } else {
                int sp = atomicAdd(spillCnt, 1);
                if (sp < SPILL_CAP)
                    spill[sp] = make_int4((esb[k] << RPS_SHIFT) + (int)(((uint_t)ex[k]) >> 17),
                                          ex[k] & 0x1FFFF, evb[k], 0);
            }
        }
        return;
    }

    // ---- gemm: h = x @ W^T + b, bf16 out; 16 rows x 128 cols per block ----
    const int blk  = blockIdx.x - nbBuild;
    const int wave = tid >> 6;
    const int lane = tid & 63;
    const int quad = lane >> 4;
    const int l16  = lane & 15;
    const int m0   = blk * 16;
    const int colbase = wave * 32;

    f32x4 acc0 = {0.f, 0.f, 0.f, 0.f};
    f32x4 acc1 = {0.f, 0.f, 0.f, 0.f};

    const float* xrow = x + (size_t)(m0 + l16) * N_IN + quad * 8;   // A: m=lane&15, k=quad*8+j
    const ushort_t* w0 = wb + (size_t)(colbase + l16) * N_IN + quad * 8;
    const ushort_t* w1 = w0 + 16 * N_IN;

    // register software pipeline: x 2 k-blocks ahead, w 1 ahead (w is L2-hot)
    float4 xa0 = *(const float4*)(xrow);
    float4 xa1 = *(const float4*)(xrow + 4);
    float4 xb0 = *(const float4*)(xrow + 32);
    float4 xb1 = *(const float4*)(xrow + 36);
    bf16x8 wbf0 = *(const bf16x8*)(w0);
    bf16x8 wbf1 = *(const bf16x8*)(w1);

    #pragma unroll
    for (int t = 0; t < 8; t++) {
        float4 ca0 = xa0, ca1 = xa1;
        bf16x8 cb0 = wbf0, cb1 = wbf1;
        xa0 = xb0; xa1 = xb1;
        if (t < 6) {
            xb0 = *(const float4*)(xrow + (t + 2) * 32);
            xb1 = *(const float4*)(xrow + (t + 2) * 32 + 4);
        }
        if (t < 7) {
            wbf0 = *(const bf16x8*)(w0 + (t + 1) * 32);
            wbf1 = *(const bf16x8*)(w1 + (t + 1) * 32);
        }
        union { bf16x8 v; __hip_bfloat162 h2[4]; } u;
        u.h2[0] = __float22bfloat162_rn(make_float2(ca0.x, ca0.y));
        u.h2[1] = __float22bfloat162_rn(make_float2(ca0.z, ca0.w));
        u.h2[2] = __float22bfloat162_rn(make_float2(ca1.x, ca1.y));
        u.h2[3] = __float22bfloat162_rn(make_float2(ca1.z, ca1.w));
        acc0 = __builtin_amdgcn_mfma_f32_16x16x32_bf16(u.v, cb0, acc0, 0, 0, 0);
        acc1 = __builtin_amdgcn_mfma_f32_16x16x32_bf16(u.v, cb1, acc1, 0, 0, 0);
    }

    // C/D: row = quad*4 + reg, col = lane&15
    const int c0 = colbase + l16;
    const int c1 = c0 + 16;
    const float bv0 = b[c0];
    const float bv1 = b[c1];
    ushort_t* hp = h16 + (size_t)(m0 + quad * 4) * N_OUTC;
    #pragma unroll
    for (int r = 0; r < 4; r++) {
        hp[(size_t)r * N_OUTC + c0] = f2bf(acc0[r] + bv0);
        hp[(size_t)r * N_OUTC + c1] = f2bf(acc1[r] + bv1);
    }
}

// ---------------- exclusive scan of clamped superbin totals (1 block, 1024 thr) ----------------
__global__ __launch_bounds__(1024) void sbscan_kernel(const int* __restrict__ sbCount, int sbCap,
                                                      int* __restrict__ sbBase, int nsb) {
    __shared__ int a[NSB_MAX], bsh[NSB_MAX];
    int tid = threadIdx.x;
    int v = 0;
    if (tid < nsb) { v = sbCount[tid]; if (v > sbCap) v = sbCap; }
    a[tid] = v; __syncthreads();
    int* src = a; int* dst = bsh;
    for (int off = 1; off < 1024; off <<= 1) {
        dst[tid] = src[tid] + ((tid >= off) ? src[tid - off] : 0);
        __syncthreads();
        int* t = src; src = dst; dst = t;
    }
    if (tid < nsb) sbBase[tid] = tid ? src[tid - 1] : 0;
}

// ---------------- sort: superbin list -> CSR (in-L2 counting sort, 64 rows/sb) ----------------
__global__ __launch_bounds__(256) void sort_kernel(const int* __restrict__ sbCount,
                                                   const int* __restrict__ sbBase,
                                                   const int2* __restrict__ sbList, int sbCap,
                                                   int2* __restrict__ csr,
                                                   int* __restrict__ rowStart, int* __restrict__ rowCnt,
                                                   int Ndst) {
    __shared__ int hist[RPS];
    __shared__ int scanA[RPS];
    __shared__ int curx[RPS];
    const int sb  = blockIdx.x;
    const int tid = threadIdx.x;
    int len = sbCount[sb]; if (len > sbCap) len = sbCap;
    const int base = sbBase[sb];
    const int2* lp = sbList + (size_t)sb * sbCap;

    if (tid < RPS) hist[tid] = 0;
    __syncthreads();

    // phase 1: histogram (4-deep prefetch)
    int i = tid;
    for (; i + 768 < len; i += 1024) {
        int x0 = lp[i].x, x1 = lp[i + 256].x, x2 = lp[i + 512].x, x3 = lp[i + 768].x;
        atomicAdd(&hist[((uint_t)x0) >> 17], 1);
        atomicAdd(&hist[((uint_t)x1) >> 17], 1);
        atomicAdd(&hist[((uint_t)x2) >> 17], 1);
        atomicAdd(&hist[((uint_t)x3) >> 17], 1);
    }
    for (; i < len; i += 256) atomicAdd(&hist[((uint_t)lp[i].x) >> 17], 1);
    __syncthreads();

    // phase 2: inclusive scan over 64 rows (predicated Hillis-Steele)
    if (tid < RPS) scanA[tid] = hist[tid];
    __syncthreads();
    for (int off = 1; off < RPS; off <<= 1) {
        int t = 0;
        if (tid < RPS) t = scanA[tid] + ((tid >= off) ? scanA[tid - off] : 0);
        __syncthreads();
        if (tid < RPS) scanA[tid] = t;
        __syncthreads();
    }
    if (tid < RPS) {
        int excl = tid ? scanA[tid - 1] : 0;
        curx[tid] = excl;
        int r = sb * RPS + tid;
        if (r < Ndst) { rowStart[r] = base + excl; rowCnt[r] = hist[tid]; }
    }
    __syncthreads();

    // phase 3: scatter (4-deep prefetch); writes stay within this sb's CSR span (L2-resident)
    i = tid;
    for (; i + 768 < len; i += 1024) {
        int2 e0 = lp[i], e1 = lp[i + 256], e2 = lp[i + 512], e3 = lp[i + 768];
        int p0 = atomicAdd(&curx[((uint_t)e0.x) >> 17], 1);
        int p1 = atomicAdd(&curx[((uint_t)e1.x) >> 17], 1);
        int p2 = atomicAdd(&curx[((uint_t)e2.x) >> 17], 1);
        int p3 = atomicAdd(&curx[((uint_t)e3.x) >> 17], 1);
        csr[(size_t)base + p0] = make_int2(e0.x & 0x1FFFF, e0.y);
        csr[(size_t)base + p1] = make_int2(e1.x & 0x1FFFF, e1.y);
        csr[(size_t)base + p2] = make_int2(e2.x & 0x1FFFF, e2.y);
        csr[(size_t)base + p3] = make_int2(e3.x & 0x1FFFF, e3.y);
    }
    for (; i < len; i += 256) {
        int2 e = lp[i];
        int pos = atomicAdd(&curx[((uint_t)e.x) >> 17], 1);
        csr[(size_t)base + pos] = make_int2(e.x & 0x1FFFF, e.y);
    }
}

// ---------------- SpMM: wave per dst row, coalesced edge loads + shfl broadcast ----------------
__global__ __launch_bounds__(256) void spmm_concat_kernel(const ushort_t* __restrict__ h16,
                                                          const int* __restrict__ rowStart,
                                                          const int* __restrict__ rowCnt,
                                                          const int2* __restrict__ csr,
                                                          const int* __restrict__ prev,
                                                          float* __restrict__ out, int Ndst) {
    int r = blockIdx.x * 4 + (threadIdx.x >> 6);
    if (r >= Ndst) return;
    const int lane = threadIdx.x & 63;
    const int cnt = rowCnt[r];
    const int2* bk = csr + rowStart[r];

    float2 acc = {0.f, 0.f};
    for (int bse = 0; bse < cnt; bse += 64) {
        int idx = bse + lane;
        int2 my = make_int2(0, 0);             // pad: v=0 -> zero contribution, c=0 safe
        if (idx < cnt) my = bk[idx];
        int m = cnt - bse; if (m > 64) m = 64;
        int mg = (m + 7) & ~7;
        for (int j = 0; j < mg; j += 8) {
            int c0 = __shfl(my.x, j + 0), c1 = __shfl(my.x, j + 1);
            int c2 = __shfl(my.x, j + 2), c3 = __shfl(my.x, j + 3);
            int c4 = __shfl(my.x, j + 4), c5 = __shfl(my.x, j + 5);
            int c6 = __shfl(my.x, j + 6), c7 = __shfl(my.x, j + 7);
            uint_t g0 = *(const uint_t*)(h16 + (size_t)c0 * N_OUTC + 2 * lane);
            uint_t g1 = *(const uint_t*)(h16 + (size_t)c1 * N_OUTC + 2 * lane);
            uint_t g2 = *(const uint_t*)(h16 + (size_t)c2 * N_OUTC + 2 * lane);
            uint_t g3 = *(const uint_t*)(h16 + (size_t)c3 * N_OUTC + 2 * lane);
            uint_t g4 = *(const uint_t*)(h16 + (size_t)c4 * N_OUTC + 2 * lane);
            uint_t g5 = *(const uint_t*)(h16 + (size_t)c5 * N_OUTC + 2 * lane);
            uint_t g6 = *(const uint_t*)(h16 + (size_t)c6 * N_OUTC + 2 * lane);
            uint_t g7 = *(const uint_t*)(h16 + (size_t)c7 * N_OUTC + 2 * lane);
            float v0 = __int_as_float(__shfl(my.y, j + 0));
            float v1 = __int_as_float(__shfl(my.y, j + 1));
            float v2 = __int_as_float(__shfl(my.y, j + 2));
            float v3 = __int_as_float(__shfl(my.y, j + 3));
            float v4 = __int_as_float(__shfl(my.y, j + 4));
            float v5 = __int_as_float(__shfl(my.y, j + 5));
            float v6 = __int_as_float(__shfl(my.y, j + 6));
            float v7 = __int_as_float(__shfl(my.y, j + 7));
            acc.x += v0 * bf_lo(g0); acc.y += v0 * bf_hi(g0);
            acc.x += v1 * bf_lo(g1); acc.y += v1 * bf_hi(g1);
            acc.x += v2 * bf_lo(g2); acc.y += v2 * bf_hi(g2);
            acc.x += v3 * bf_lo(g3); acc.y += v3 * bf_hi(g3);
            acc.x += v4 * bf_lo(g4); acc.y += v4 * bf_hi(g4);
            acc.x += v5 * bf_lo(g5); acc.y += v5 * bf_hi(g5);
            acc.x += v6 * bf_lo(g6); acc.y += v6 * bf_hi(g6);
            acc.x += v7 * bf_lo(g7); acc.y += v7 * bf_hi(g7);
        }
    }

    int p = prev[r];
    uint_t g = *(const uint_t*)(h16 + (size_t)p * N_OUTC + 2 * lane);
    float2* o = (float2*)(out + (size_t)r * 256);
    o[lane]      = make_float2(bf_lo(g), bf_hi(g));
    o[64 + lane] = make_float2(acc.x, acc.y);
}

// ---------------- spill fixup (expected empty) ----------------
__global__ void spill_kernel(const ushort_t* __restrict__ h16, const int4* __restrict__ spill,
                             const int* __restrict__ spillCnt, float* __restrict__ out) {
    int n = *spillCnt; if (n > SPILL_CAP) n = SPILL_CAP;
    int total = n * 64;
    for (int t = blockIdx.x * blockDim.x + threadIdx.x; t < total; t += gridDim.x * blockDim.x) {
        int idx = t >> 6, lane = t & 63;
        int4 s = spill[idx];
        uint_t g = *(const uint_t*)(h16 + (size_t)s.y * N_OUTC + 2 * lane);
        float v = __int_as_float(s.z);
        atomicAdd(&out[(size_t)s.x * 256 + 128 + 2 * lane],     v * bf_lo(g));
        atomicAdd(&out[(size_t)s.x * 256 + 128 + 2 * lane + 1], v * bf_hi(g));
    }
}

// ---------------- fallback path (ws too small; not expected) ----------------
__global__ __launch_bounds__(256) void gemm_only_kernel(const float* __restrict__ x,
                                                        const ushort_t* __restrict__ wb,
                                                        const float* __restrict__ b,
                                                        ushort_t* __restrict__ h16) {
    const int tid  = threadIdx.x;
    const int wave = tid >> 6;
    const int lane = tid & 63;
    const int quad = lane >> 4;
    const int l16  = lane & 15;
    const int m0   = blockIdx.x * 16;
    const int colbase = wave * 32;
    f32x4 acc0 = {0.f, 0.f, 0.f, 0.f};
    f32x4 acc1 = {0.f, 0.f, 0.f, 0.f};
    const float* xrow = x + (size_t)(m0 + l16) * N_IN + quad * 8;
    const ushort_t* w0 = wb + (size_t)(colbase + l16) * N_IN + quad * 8;
    const ushort_t* w1 = w0 + 16 * N_IN;
    #pragma unroll
    for (int kb = 0; kb < N_IN; kb += 32) {
        float4 a0 = *(const float4*)(xrow + kb);
        float4 a1 = *(const float4*)(xrow + kb + 4);
        union { bf16x8 v; __hip_bfloat162 h2[4]; } u;
        u.h2[0] = __float22bfloat162_rn(make_float2(a0.x, a0.y));
        u.h2[1] = __float22bfloat162_rn(make_float2(a0.z, a0.w));
        u.h2[2] = __float22bfloat162_rn(make_float2(a1.x, a1.y));
        u.h2[3] = __float22bfloat162_rn(make_float2(a1.z, a1.w));
        bf16x8 bf0 = *(const bf16x8*)(w0 + kb);
        bf16x8 bf1 = *(const bf16x8*)(w1 + kb);
        acc0 = __builtin_amdgcn_mfma_f32_16x16x32_bf16(u.v, bf0, acc0, 0, 0, 0);
        acc1 = __builtin_amdgcn_mfma_f32_16x16x32_bf16(u.v, bf1, acc1, 0, 0, 0);
    }
    const int c0 = colbase + l16;
    const int c1 = c0 + 16;
    const float bv0 = b[c0];
    const float bv1 = b[c1];
    ushort_t* hp = h16 + (size_t)(m0 + quad * 4) * N_OUTC;
    #pragma unroll
    for (int r = 0; r < 4; r++) {
        hp[(size_t)r * N_OUTC + c0] = f2bf(acc0[r] + bv0);
        hp[(size_t)r * N_OUTC + c1] = f2bf(acc1[r] + bv1);
    }
}

__global__ void concat_only_kernel(const ushort_t* __restrict__ h16, const int* __restrict__ prev,
                                   float* __restrict__ out, int Ndst) {
    int t = blockIdx.x * blockDim.x + threadIdx.x;
    int r = t >> 6, lane = t & 63;
    if (r >= Ndst) return;
    uint_t g = *(const uint_t*)(h16 + (size_t)prev[r] * N_OUTC + 2 * lane);
    ((float2*)out)[(size_t)r * 128 + lane] = make_float2(bf_lo(g), bf_hi(g));
}

__global__ void spmm_atomic_kernel(const ushort_t* __restrict__ h16, const int* __restrict__ rows,
                                   const int* __restrict__ cols, const float* __restrict__ vals,
                                   int E, float* __restrict__ out) {
    long long t = (long long)blockIdx.x * blockDim.x + threadIdx.x;
    int e = (int)(t >> 6), lane = (int)(t & 63);
    if (e >= E) return;
    uint_t g = *(const uint_t*)(h16 + (size_t)cols[e] * N_OUTC + 2 * lane);
    float v = vals[e];
    int r = rows[e];
    atomicAdd(&out[(size_t)r * 256 + 128 + 2 * lane],     v * bf_lo(g));
    atomicAdd(&out[(size_t)r * 256 + 128 + 2 * lane + 1], v * bf_hi(g));
}

extern "C" void kernel_launch(void* const* d_in, const int* in_sizes, int n_in,
                              void* d_out, int out_size, void* d_ws, size_t ws_size,
                              hipStream_t stream) {
    const float* x    = (const float*)d_in[0];
    const float* W    = (const float*)d_in[1];
    const float* b    = (const float*)d_in[2];
    const float* vals = (const float*)d_in[3];
    const int*   rows = (const int*)d_in[4];
    const int*   cols = (const int*)d_in[5];
    const int*   prev = (const int*)d_in[6];
    float* out = (float*)d_out;

    const int Nsrc = in_sizes[0] / N_IN;   // 100000
    const int E    = in_sizes[3];          // 3200000
    const int Ndst = in_sizes[6];          // 50000
    const int NSB  = (Ndst + RPS - 1) / RPS;           // 782
    const int sbCap = E / NSB + 516;                   // mean ~4092 + 8 sigma
    const int nbBuild = (E + TILE - 1) / TILE;         // 782
    const int gemmBlocks = Nsrc / 16;                  // 6250

    char* ws = (char*)d_ws;
    size_t off = 0;
    ushort_t* h16 = (ushort_t*)(ws + off);
    off += (size_t)Nsrc * N_OUTC * sizeof(ushort_t);               // 25.6 MB
    ushort_t* wb = (ushort_t*)(ws + off);
    off += (size_t)N_OUTC * N_IN * sizeof(ushort_t);               // 64 KB
    off = (off + 255) & ~(size_t)255;
    int* sbCount  = (int*)(ws + off);                               // memset zone: NSB + 1
    int* spillCnt = sbCount + NSB;
    size_t memsetBytes = ((size_t)NSB + 1) * sizeof(int);
    off += memsetBytes;
    off = (off + 255) & ~(size_t)255;
    int* sbBase = (int*)(ws + off);
    off += (size_t)NSB * sizeof(int);
    off = (off + 255) & ~(size_t)255;
    int* rowStart = (int*)(ws + off);
    off += (size_t)Ndst * sizeof(int);
    int* rowCnt = (int*)(ws + off);
    off += (size_t)Ndst * sizeof(int);
    off = (off + 255) & ~(size_t)255;
    int4* spill = (int4*)(ws + off);
    off += (size_t)SPILL_CAP * sizeof(int4);
    off = (off + 255) & ~(size_t)255;
    int2* sbList = (int2*)(ws + off);
    off += (size_t)NSB * sbCap * sizeof(int2);                     // ~28.8 MB
    off = (off + 255) & ~(size_t)255;
    int2* csr = (int2*)(ws + off);
    off += (size_t)E * sizeof(int2);                               // 25.6 MB

    cvtW_kernel<<<(N_OUTC * N_IN + 255) / 256, 256, 0, stream>>>(W, wb, N_OUTC * N_IN);

    if (off <= ws_size && NSB <= NSB_MAX) {
        hipMemsetAsync(sbCount, 0, memsetBytes, stream);
        fused_build_gemm_kernel<<<nbBuild + gemmBlocks, 256, 0, stream>>>(
            rows, cols, vals, E, sbCount, sbList, sbCap, NSB, spillCnt, spill, nbBuild,
            x, wb, b, h16);
        sbscan_kernel<<<1, 1024, 0, stream>>>(sbCount, sbCap, sbBase, NSB);
        sort_kernel<<<NSB, 256, 0, stream>>>(sbCount, sbBase, sbList, sbCap,
                                             csr, rowStart, rowCnt, Ndst);
        spmm_concat_kernel<<<(Ndst + 3) / 4, 256, 0, stream>>>(h16, rowStart, rowCnt, csr,
                                                               prev, out, Ndst);
        spill_kernel<<<64, 256, 0, stream>>>(h16, spill, spillCnt, out);
    } else {
        gemm_only_kernel<<<gemmBlocks, 256, 0, stream>>>(x, wb, b, h16);
        hipMemsetAsync(out, 0, (size_t)out_size * sizeof(float), stream);
        concat_only_kernel<<<((size_t)Ndst * 64 + 255) / 256, 256, 0, stream>>>(h16, prev, out, Ndst);
        spmm_atomic_kernel<<<((size_t)E * 64 + 255) / 256, 256, 0, stream>>>(h16, rows, cols, vals, E, out);
    }
}